// Round 12
// baseline (2258.724 us; speedup 1.0000x reference)
//
#include <hip/hip_runtime.h>
#include <math.h>

#define NN 50000
#define EE 1600000
#define FIN 32
#define HID_ 128
#define ED_ 16
#define GG 512
#define MH_ 512
#define MO_ 512

typedef float v2f __attribute__((ext_vector_type(2)));

#if __has_builtin(__builtin_amdgcn_exp2f)
#define EXP2(x) __builtin_amdgcn_exp2f(x)
#else
#define EXP2(x) exp2f(x)
#endif

// DPP-based add of a lane-permuted value (no LDS, no waitcnt).
template <int CTRL>
__device__ __forceinline__ float dpp_add(float x) {
  int m = __builtin_amdgcn_update_dpp(0, __float_as_int(x), CTRL, 0xF, 0xF, true);
  return x + __int_as_float(m);
}

// sum within 8-lane groups: xor1, xor2, then half-row mirror (adds opposite quad)
__device__ __forceinline__ float bfly8(float p) {
  p = dpp_add<0xB1>(p);   // quad_perm [1,0,3,2]  (lane^1)
  p = dpp_add<0x4E>(p);   // quad_perm [2,3,0,1]  (lane^2)
  p = dpp_add<0x141>(p);  // row_half_mirror      (adds other quad of the 8-group)
  return p;
}

// ---------------- CSR build ----------------

// histogram + loop_attr accumulation in one pass.
// Edge-per-thread: ea row read is sequential in e (coalesced stream),
// accumulation via float atomics into laS[dst] (order-insensitive to 1ulp-ish).
__global__ void hist_la_kernel(const int* __restrict__ dst, const float4* __restrict__ ea4,
                               int* __restrict__ cnt, float* __restrict__ laS) {
  int e = blockIdx.x * 256 + threadIdx.x;
  if (e >= EE) return;
  int v = dst[e];
  atomicAdd(&cnt[v], 1);
  float* lp = laS + (size_t)v * 16;
  float4 q0 = ea4[e * 4 + 0], q1 = ea4[e * 4 + 1];
  float4 q2 = ea4[e * 4 + 2], q3 = ea4[e * 4 + 3];
  atomicAdd(lp + 0, q0.x);  atomicAdd(lp + 1, q0.y);
  atomicAdd(lp + 2, q0.z);  atomicAdd(lp + 3, q0.w);
  atomicAdd(lp + 4, q1.x);  atomicAdd(lp + 5, q1.y);
  atomicAdd(lp + 6, q1.z);  atomicAdd(lp + 7, q1.w);
  atomicAdd(lp + 8, q2.x);  atomicAdd(lp + 9, q2.y);
  atomicAdd(lp + 10, q2.z); atomicAdd(lp + 11, q2.w);
  atomicAdd(lp + 12, q3.x); atomicAdd(lp + 13, q3.y);
  atomicAdd(lp + 14, q3.z); atomicAdd(lp + 15, q3.w);
}

__global__ void norm_la_kernel(const float* __restrict__ laS, const int* __restrict__ cnt,
                               float* __restrict__ la) {
  int t = blockIdx.x * 256 + threadIdx.x;
  if (t >= NN * 16) return;
  int v = t >> 4;
  int d = cnt[v];
  la[t] = (d > 0) ? laS[t] / (float)d : 0.f;
}

__global__ __launch_bounds__(256) void scan1_kernel(const int* __restrict__ in, int n,
                                                    int* __restrict__ out,
                                                    int* __restrict__ bsums) {
  int chunk = blockIdx.x;
  int base = chunk * 1024;
  int t = threadIdx.x;
  int idx = base + t * 4;
  int v0 = (idx + 0 < n) ? in[idx + 0] : 0;
  int v1 = (idx + 1 < n) ? in[idx + 1] : 0;
  int v2 = (idx + 2 < n) ? in[idx + 2] : 0;
  int v3 = (idx + 3 < n) ? in[idx + 3] : 0;
  int ts = v0 + v1 + v2 + v3;
  int lane = t & 63, w = t >> 6;
  int s = ts;
#pragma unroll
  for (int off = 1; off < 64; off <<= 1) {
    int o = __shfl_up(s, off);
    if (lane >= off) s += o;
  }
  __shared__ int wsum[4];
  if (lane == 63) wsum[w] = s;
  __syncthreads();
  int woff = 0;
  for (int i = 0; i < w; i++) woff += wsum[i];
  int excl = woff + s - ts;
  int run = excl;
  run += v0; if (idx + 0 < n) out[idx + 0] = run;
  run += v1; if (idx + 1 < n) out[idx + 1] = run;
  run += v2; if (idx + 2 < n) out[idx + 2] = run;
  run += v3; if (idx + 3 < n) out[idx + 3] = run;
  if (t == 255) bsums[chunk] = woff + s;
}

__global__ void scan_add_kernel(int* __restrict__ rowptr, const int* __restrict__ bscan, int n) {
  int i = blockIdx.x * 256 + threadIdx.x;
  if (i == 0) rowptr[0] = 0;
  if (i < n) {
    int chunk = i >> 10;
    if (chunk > 0) rowptr[1 + i] += bscan[chunk - 1];
  }
}

__global__ void scatter_kernel(const int4* __restrict__ src4, const int4* __restrict__ dst4,
                               const int* __restrict__ rowptr, int* __restrict__ fill,
                               int2* __restrict__ csr) {
  int e = blockIdx.x * 256 + threadIdx.x;
  if (e >= EE / 4) return;
  int4 s = src4[e];
  int4 d = dst4[e];
  int eb = e * 4;
  int p0 = rowptr[d.x] + atomicAdd(&fill[d.x], 1);
  csr[p0] = make_int2(s.x, eb + 0);
  int p1 = rowptr[d.y] + atomicAdd(&fill[d.y], 1);
  csr[p1] = make_int2(s.y, eb + 1);
  int p2 = rowptr[d.z] + atomicAdd(&fill[d.z], 1);
  csr[p2] = make_int2(s.z, eb + 2);
  int p3 = rowptr[d.w] + atomicAdd(&fill[d.w], 1);
  csr[p3] = make_int2(s.w, eb + 3);
}

// ---------------- node linear transforms (packed f32, pad-34 LDS) ----------------

template <int F>
__global__ __launch_bounds__(256) void node_transform(const float* __restrict__ h,
                                                      const float* __restrict__ Wlm,
                                                      const float* __restrict__ blm,
                                                      const float* __restrict__ Wrm,
                                                      const float* __restrict__ brm,
                                                      float* __restrict__ xl,
                                                      float* __restrict__ xr, int nnodes) {
  __shared__ float hs[F * 34];  // [k][i] stride 34
  int v0 = blockIdx.x * 32;
  int t = threadIdx.x;
  for (int idx = t; idx < 32 * F; idx += 256) {
    int i = idx / F, k = idx - i * F;
    hs[k * 34 + i] = (v0 + i < nnodes) ? h[(size_t)(v0 + i) * F + k] : 0.f;
  }
  __syncthreads();
  bool isL = t < 128;
  int q = t & 63;          // channel pair
  int nh = (t >> 6) & 1;   // node half
  const float* Wm = isL ? Wlm : Wrm;
  v2f acc[16];
#pragma unroll
  for (int i = 0; i < 16; i++) acc[i] = (v2f){0.f, 0.f};
  for (int k = 0; k < F; k++) {
    v2f w = *(const v2f*)(Wm + k * 128 + 2 * q);
    const v2f* hk2 = (const v2f*)(hs + k * 34 + nh * 16);
#pragma unroll
    for (int r = 0; r < 8; r++) {
      v2f hv = hk2[r];
      acc[2 * r + 0] = __builtin_elementwise_fma((v2f){hv.x, hv.x}, w, acc[2 * r + 0]);
      acc[2 * r + 1] = __builtin_elementwise_fma((v2f){hv.y, hv.y}, w, acc[2 * r + 1]);
    }
  }
  const float* bm = isL ? blm : brm;
  v2f b = *(const v2f*)(bm + 2 * q);
  float* dstp = isL ? xl : xr;
  int base = v0 + nh * 16;
#pragma unroll
  for (int i = 0; i < 16; i++) {
    if (base + i < nnodes)
      *(v2f*)(dstp + (size_t)(base + i) * 128 + 2 * q) = acc[i] + b;
  }
}

// ---------------- GATv2 edge scoring + softmax aggregation ----------------
// EXACT round-7 structure (best measured: 161us/dispatch, FETCH 496MB):
// one wave per node; lane owns channels (2l,2l+1); wec[16] v2f loaded
// up-front; self-loop FIRST; interleaved 4-edge unroll; DPP 8-lane
// reductions; no max-tracking (exact-equivalent in f32 at these scales).

__global__ __launch_bounds__(256) void gat_aggregate(
    const float* __restrict__ xl, const float* __restrict__ xr,
    const int* __restrict__ rowptr, const int2* __restrict__ csr,
    const float* __restrict__ ea, const float* __restrict__ la,
    const float* __restrict__ We, const float* __restrict__ att,
    const float* __restrict__ bias, float* __restrict__ hout, int relu) {
  int wid = threadIdx.x >> 6, lane = threadIdx.x & 63;
  int v = __builtin_amdgcn_readfirstlane(blockIdx.x * 4 + wid);
  if (v >= NN) return;
  int c = 2 * lane;
  v2f wec[16];
#pragma unroll
  for (int k = 0; k < 16; k++) wec[k] = *(const v2f*)(We + k * 128 + c);
  const float L2E = 1.44269504088896340736f;
  v2f av = *(const v2f*)(att + c) * L2E;
  v2f xrv = *(const v2f*)(xr + (size_t)v * 128 + c);

  auto score = [&](int u, const float* eaP, v2f& xu) -> float {
    xu = *(const v2f*)(xl + (size_t)u * 128 + c);
    v2f m = xrv + xu;
#pragma unroll
    for (int k = 0; k < 16; k++) {
      float e = eaP[k];  // wave-uniform -> scalar load
      m = __builtin_elementwise_fma((v2f){e, e}, wec[k], m);
    }
    m = __builtin_elementwise_max(m, 0.2f * m);  // LeakyReLU
    v2f qq = av * m;
    return bfly8(qq.x + qq.y);
  };

  v2f acc;
  float den;
  {  // self loop
    v2f xu;
    float p = score(v, la + (size_t)v * 16, xu);
    float w = EXP2(p);
    den = w;
    acc = (v2f){w, w} * xu;
  }
  int start = __builtin_amdgcn_readfirstlane(rowptr[v]);
  int end = __builtin_amdgcn_readfirstlane(rowptr[v + 1]);
  int j = start;
  for (; j + 4 <= end; j += 4) {
    int2 e0 = csr[j], e1 = csr[j + 1], e2 = csr[j + 2], e3 = csr[j + 3];
    int u0 = __builtin_amdgcn_readfirstlane(e0.x);
    int u1 = __builtin_amdgcn_readfirstlane(e1.x);
    int u2 = __builtin_amdgcn_readfirstlane(e2.x);
    int u3 = __builtin_amdgcn_readfirstlane(e3.x);
    const float* p0 = ea + (size_t)__builtin_amdgcn_readfirstlane(e0.y) * 16;
    const float* p1 = ea + (size_t)__builtin_amdgcn_readfirstlane(e1.y) * 16;
    const float* p2 = ea + (size_t)__builtin_amdgcn_readfirstlane(e2.y) * 16;
    const float* p3 = ea + (size_t)__builtin_amdgcn_readfirstlane(e3.y) * 16;
    v2f x0, x1, x2, x3;
    float s0 = score(u0, p0, x0);
    float s1 = score(u1, p1, x1);
    float s2 = score(u2, p2, x2);
    float s3 = score(u3, p3, x3);
    float w0 = EXP2(s0), w1 = EXP2(s1), w2 = EXP2(s2), w3 = EXP2(s3);
    den += (w0 + w1) + (w2 + w3);
    acc = __builtin_elementwise_fma((v2f){w0, w0}, x0,
          __builtin_elementwise_fma((v2f){w1, w1}, x1,
          __builtin_elementwise_fma((v2f){w2, w2}, x2,
          __builtin_elementwise_fma((v2f){w3, w3}, x3, acc))));
  }
  for (; j < end; ++j) {
    int2 e0 = csr[j];
    int u = __builtin_amdgcn_readfirstlane(e0.x);
    const float* p0 = ea + (size_t)__builtin_amdgcn_readfirstlane(e0.y) * 16;
    v2f xu;
    float p = score(u, p0, xu);
    float w = EXP2(p);
    den += w;
    acc = __builtin_elementwise_fma((v2f){w, w}, xu, acc);
  }
  float invd = 1.f / den;
  v2f bv = *(const v2f*)(bias + c);
  v2f o = __builtin_elementwise_fma(acc, (v2f){invd, invd}, bv);
  if (relu) o = __builtin_elementwise_max(o, (v2f){0.f, 0.f});
  *(v2f*)(hout + (size_t)v * 128 + c) = o;
}

// ---------------- pooling + MLP ----------------

__global__ void gptr_kernel(const int* __restrict__ batch, int* __restrict__ gptr) {
  int g = blockIdx.x * 256 + threadIdx.x;
  if (g > GG) return;
  int lo = 0, hi = NN;
  while (lo < hi) {
    int mid = (lo + hi) >> 1;
    if (batch[mid] < g) lo = mid + 1; else hi = mid;
  }
  gptr[g] = lo;
}

__global__ void pool_kernel(const float* __restrict__ h, const int* __restrict__ gptr,
                            float* __restrict__ gp) {
  int gi = blockIdx.x;
  int c = threadIdx.x;  // 128
  int s = gptr[gi], e = gptr[gi + 1];
  float acc = 0.f;
  for (int v = s; v < e; v++) acc += h[(size_t)v * 128 + c];
  gp[gi * 128 + c] = acc;
}

__global__ __launch_bounds__(256) void mlp1_kernel(const float* __restrict__ gp,
                                                   const float* __restrict__ mW1,
                                                   const float* __restrict__ mb1,
                                                   const float* __restrict__ lng,
                                                   const float* __restrict__ lnb,
                                                   float* __restrict__ z) {
  int row = blockIdx.x;
  int t = threadIdx.x;
  __shared__ float gs[128];
  if (t < 128) gs[t] = gp[row * 128 + t];
  __syncthreads();
  int c0 = t, c1 = t + 256;
  float z0 = 0.f, z1 = 0.f;
  for (int k = 0; k < 128; k++) {
    float gk = gs[k];
    z0 = fmaf(gk, mW1[k * 512 + c0], z0);
    z1 = fmaf(gk, mW1[k * 512 + c1], z1);
  }
  z0 += mb1[c0]; z1 += mb1[c1];
  z0 = fmaxf(z0, 0.f); z1 = fmaxf(z1, 0.f);
  float s = z0 + z1, q = z0 * z0 + z1 * z1;
#pragma unroll
  for (int off = 32; off > 0; off >>= 1) {
    s += __shfl_xor(s, off);
    q += __shfl_xor(q, off);
  }
  __shared__ float red[8];
  int lane = t & 63, w = t >> 6;
  if (lane == 0) { red[w] = s; red[4 + w] = q; }
  __syncthreads();
  float S = red[0] + red[1] + red[2] + red[3];
  float Q = red[4] + red[5] + red[6] + red[7];
  float mu = S / 512.f;
  float var = Q / 512.f - mu * mu;
  float inv = 1.f / sqrtf(var + 1e-5f);
  z[row * 512 + c0] = (z0 - mu) * inv * lng[c0] + lnb[c0];
  z[row * 512 + c1] = (z1 - mu) * inv * lng[c1] + lnb[c1];
}

__global__ __launch_bounds__(256) void mlp2_kernel(const float* __restrict__ z,
                                                   const float* __restrict__ mW2,
                                                   const float* __restrict__ mb2,
                                                   float* __restrict__ out) {
  int row = blockIdx.x;
  int t = threadIdx.x;
  __shared__ float zs[512];
  for (int i = t; i < 512; i += 256) zs[i] = z[row * 512 + i];
  __syncthreads();
  int c0 = t, c1 = t + 256;
  float o0 = 0.f, o1 = 0.f;
  for (int k = 0; k < 512; k++) {
    float zk = zs[k];
    o0 = fmaf(zk, mW2[k * 512 + c0], o0);
    o1 = fmaf(zk, mW2[k * 512 + c1], o1);
  }
  out[row * 512 + c0] = o0 + mb2[c0];
  out[row * 512 + c1] = o1 + mb2[c1];
}

// ---------------- launcher ----------------

extern "C" void kernel_launch(void* const* d_in, const int* in_sizes, int n_in,
                              void* d_out, int out_size, void* d_ws, size_t ws_size,
                              hipStream_t stream) {
  const float* x = (const float*)d_in[0];
  const int* ei = (const int*)d_in[1];
  const int* srcE = ei;
  const int* dstE = ei + EE;
  const float* ea = (const float*)d_in[2];
  const int* batch = (const int*)d_in[3];
  const float* Wl[3] = {(const float*)d_in[4], (const float*)d_in[11], (const float*)d_in[18]};
  const float* bl[3] = {(const float*)d_in[5], (const float*)d_in[12], (const float*)d_in[19]};
  const float* Wr[3] = {(const float*)d_in[6], (const float*)d_in[13], (const float*)d_in[20]};
  const float* br[3] = {(const float*)d_in[7], (const float*)d_in[14], (const float*)d_in[21]};
  const float* Wek[3] = {(const float*)d_in[8], (const float*)d_in[15], (const float*)d_in[22]};
  const float* attk[3] = {(const float*)d_in[9], (const float*)d_in[16], (const float*)d_in[23]};
  const float* bk[3] = {(const float*)d_in[10], (const float*)d_in[17], (const float*)d_in[24]};
  const float* mW1 = (const float*)d_in[25];
  const float* mb1 = (const float*)d_in[26];
  const float* lng = (const float*)d_in[27];
  const float* lnb = (const float*)d_in[28];
  const float* mW2 = (const float*)d_in[29];
  const float* mb2 = (const float*)d_in[30];
  float* outp = (float*)d_out;

  char* W = (char*)d_ws;
  size_t off = 0;
  auto take = [&](size_t b) -> void* {
    void* p = W + off;
    off += (b + 255) & ~(size_t)255;
    return p;
  };
  int* cnt = (int*)take(NN * 4);
  int* rowptr = (int*)take((NN + 1) * 4);
  int* bsums = (int*)take(64 * 4);
  int* bscan = (int*)take(64 * 4);
  int* dummy = (int*)take(64 * 4);
  int2* csr = (int2*)take((size_t)EE * 8);
  float* laS = (float*)take((size_t)NN * 16 * 4);
  float* la = (float*)take((size_t)NN * 16 * 4);
  float* xl = (float*)take((size_t)NN * HID_ * 4);
  float* xr = (float*)take((size_t)NN * HID_ * 4);
  float* hbuf = (float*)take((size_t)NN * HID_ * 4);
  int* gptr = (int*)take((GG + 1) * 4);
  float* gpool = (float*)take((size_t)GG * HID_ * 4);
  float* z = (float*)take((size_t)GG * MH_ * 4);
  (void)ws_size; (void)n_in; (void)in_sizes; (void)out_size;

  // CSR build + loop_attr
  hipMemsetAsync(cnt, 0, NN * 4, stream);
  hipMemsetAsync(laS, 0, (size_t)NN * 16 * 4, stream);
  hist_la_kernel<<<(EE + 255) / 256, 256, 0, stream>>>(dstE, (const float4*)ea, cnt, laS);
  scan1_kernel<<<49, 256, 0, stream>>>(cnt, NN, rowptr + 1, bsums);
  scan1_kernel<<<1, 256, 0, stream>>>(bsums, 49, bscan, dummy);
  scan_add_kernel<<<(NN + 255) / 256, 256, 0, stream>>>(rowptr, bscan, NN);
  norm_la_kernel<<<(NN * 16 + 255) / 256, 256, 0, stream>>>(laS, cnt, la);
  hipMemsetAsync(cnt, 0, NN * 4, stream);
  scatter_kernel<<<(EE / 4 + 255) / 256, 256, 0, stream>>>((const int4*)srcE, (const int4*)dstE,
                                                           rowptr, cnt, csr);

  // 3 GATv2 layers
  for (int l = 0; l < 3; l++) {
    if (l == 0)
      node_transform<FIN><<<(NN + 31) / 32, 256, 0, stream>>>(x, Wl[0], bl[0], Wr[0], br[0],
                                                              xl, xr, NN);
    else
      node_transform<HID_><<<(NN + 31) / 32, 256, 0, stream>>>(hbuf, Wl[l], bl[l], Wr[l], br[l],
                                                               xl, xr, NN);
    gat_aggregate<<<(NN + 3) / 4, 256, 0, stream>>>(xl, xr, rowptr, csr, ea, la,
                                                    Wek[l], attk[l], bk[l], hbuf,
                                                    (l < 2) ? 1 : 0);
  }

  // pooling + MLP head
  gptr_kernel<<<3, 256, 0, stream>>>(batch, gptr);
  pool_kernel<<<GG, 128, 0, stream>>>(hbuf, gptr, gpool);
  mlp1_kernel<<<GG, 256, 0, stream>>>(gpool, mW1, mb1, lng, lnb, z);
  mlp2_kernel<<<GG, 256, 0, stream>>>(z, mW2, mb2, outp);
}

// Round 13
// 881.110 us; speedup vs baseline: 2.5635x; 2.5635x over previous
//
#include <hip/hip_runtime.h>
#include <hip/hip_fp16.h>
#include <math.h>

#define NN 50000
#define EE 1600000
#define FIN 32
#define HID_ 128
#define ED_ 16
#define GG 512
#define MH_ 512
#define MO_ 512

typedef float v2f __attribute__((ext_vector_type(2)));

#if __has_builtin(__builtin_amdgcn_exp2f)
#define EXP2(x) __builtin_amdgcn_exp2f(x)
#else
#define EXP2(x) exp2f(x)
#endif

// DPP-based add of a lane-permuted value (no LDS, no waitcnt).
template <int CTRL>
__device__ __forceinline__ float dpp_add(float x) {
  int m = __builtin_amdgcn_update_dpp(0, __float_as_int(x), CTRL, 0xF, 0xF, true);
  return x + __int_as_float(m);
}

// sum within 8-lane groups: xor1, xor2, then half-row mirror (adds opposite quad)
__device__ __forceinline__ float bfly8(float p) {
  p = dpp_add<0xB1>(p);   // quad_perm [1,0,3,2]  (lane^1)
  p = dpp_add<0x4E>(p);   // quad_perm [2,3,0,1]  (lane^2)
  p = dpp_add<0x141>(p);  // row_half_mirror      (adds other quad of the 8-group)
  return p;
}

__device__ __forceinline__ v2f h2f(__half2 h) {
  float2 f = __half22float2(h);
  return (v2f){f.x, f.y};
}

// ---------------- CSR build ----------------

__global__ void hist_kernel(const int4* __restrict__ dst4, int* __restrict__ cnt) {
  int e = blockIdx.x * 256 + threadIdx.x;
  if (e >= EE / 4) return;
  int4 d = dst4[e];
  atomicAdd(&cnt[d.x], 1);
  atomicAdd(&cnt[d.y], 1);
  atomicAdd(&cnt[d.z], 1);
  atomicAdd(&cnt[d.w], 1);
}

__global__ __launch_bounds__(256) void scan1_kernel(const int* __restrict__ in, int n,
                                                    int* __restrict__ out,
                                                    int* __restrict__ bsums) {
  int chunk = blockIdx.x;
  int base = chunk * 1024;
  int t = threadIdx.x;
  int idx = base + t * 4;
  int v0 = (idx + 0 < n) ? in[idx + 0] : 0;
  int v1 = (idx + 1 < n) ? in[idx + 1] : 0;
  int v2 = (idx + 2 < n) ? in[idx + 2] : 0;
  int v3 = (idx + 3 < n) ? in[idx + 3] : 0;
  int ts = v0 + v1 + v2 + v3;
  int lane = t & 63, w = t >> 6;
  int s = ts;
#pragma unroll
  for (int off = 1; off < 64; off <<= 1) {
    int o = __shfl_up(s, off);
    if (lane >= off) s += o;
  }
  __shared__ int wsum[4];
  if (lane == 63) wsum[w] = s;
  __syncthreads();
  int woff = 0;
  for (int i = 0; i < w; i++) woff += wsum[i];
  int excl = woff + s - ts;
  int run = excl;
  run += v0; if (idx + 0 < n) out[idx + 0] = run;
  run += v1; if (idx + 1 < n) out[idx + 1] = run;
  run += v2; if (idx + 2 < n) out[idx + 2] = run;
  run += v3; if (idx + 3 < n) out[idx + 3] = run;
  if (t == 255) bsums[chunk] = woff + s;
}

__global__ void scan_add_kernel(int* __restrict__ rowptr, const int* __restrict__ bscan, int n) {
  int i = blockIdx.x * 256 + threadIdx.x;
  if (i == 0) rowptr[0] = 0;
  if (i < n) {
    int chunk = i >> 10;
    if (chunk > 0) rowptr[1 + i] += bscan[chunk - 1];
  }
}

__global__ void scatter_kernel(const int4* __restrict__ src4, const int4* __restrict__ dst4,
                               const int* __restrict__ rowptr, int* __restrict__ fill,
                               int2* __restrict__ csr) {
  int e = blockIdx.x * 256 + threadIdx.x;
  if (e >= EE / 4) return;
  int4 s = src4[e];
  int4 d = dst4[e];
  int eb = e * 4;
  int p0 = rowptr[d.x] + atomicAdd(&fill[d.x], 1);
  csr[p0] = make_int2(s.x, eb + 0);
  int p1 = rowptr[d.y] + atomicAdd(&fill[d.y], 1);
  csr[p1] = make_int2(s.y, eb + 1);
  int p2 = rowptr[d.z] + atomicAdd(&fill[d.z], 1);
  csr[p2] = make_int2(s.z, eb + 2);
  int p3 = rowptr[d.w] + atomicAdd(&fill[d.w], 1);
  csr[p3] = make_int2(s.w, eb + 3);
}

// ---------------- node linear transforms (packed f32, pad-34 LDS, fp16 out) ----------------

template <int F>
__global__ __launch_bounds__(256) void node_transform(const float* __restrict__ h,
                                                      const float* __restrict__ Wlm,
                                                      const float* __restrict__ blm,
                                                      const float* __restrict__ Wrm,
                                                      const float* __restrict__ brm,
                                                      __half2* __restrict__ xl,
                                                      __half2* __restrict__ xr, int nnodes) {
  __shared__ float hs[F * 34];  // [k][i] stride 34
  int v0 = blockIdx.x * 32;
  int t = threadIdx.x;
  for (int idx = t; idx < 32 * F; idx += 256) {
    int i = idx / F, k = idx - i * F;
    hs[k * 34 + i] = (v0 + i < nnodes) ? h[(size_t)(v0 + i) * F + k] : 0.f;
  }
  __syncthreads();
  bool isL = t < 128;
  int q = t & 63;          // channel pair
  int nh = (t >> 6) & 1;   // node half
  const float* Wm = isL ? Wlm : Wrm;
  v2f acc[16];
#pragma unroll
  for (int i = 0; i < 16; i++) acc[i] = (v2f){0.f, 0.f};
  for (int k = 0; k < F; k++) {
    v2f w = *(const v2f*)(Wm + k * 128 + 2 * q);
    const v2f* hk2 = (const v2f*)(hs + k * 34 + nh * 16);
#pragma unroll
    for (int r = 0; r < 8; r++) {
      v2f hv = hk2[r];
      acc[2 * r + 0] = __builtin_elementwise_fma((v2f){hv.x, hv.x}, w, acc[2 * r + 0]);
      acc[2 * r + 1] = __builtin_elementwise_fma((v2f){hv.y, hv.y}, w, acc[2 * r + 1]);
    }
  }
  const float* bm = isL ? blm : brm;
  v2f b = *(const v2f*)(bm + 2 * q);
  __half2* dstp = isL ? xl : xr;
  int base = v0 + nh * 16;
#pragma unroll
  for (int i = 0; i < 16; i++) {
    if (base + i < nnodes) {
      v2f o = acc[i] + b;
      dstp[(size_t)(base + i) * 64 + q] = __floats2half2_rn(o.x, o.y);
    }
  }
}

// ---------------- GATv2 edge scoring + softmax aggregation ----------------
// Round-7 body (best measured), with xl/xr stored fp16 (__half2 per lane) to
// halve the dominant per-edge gather traffic. Logit math, ea rows, softmax
// accumulation all stay f32. No max-tracking (exact-equivalent at these
// scales). LAYER0=1: fuses loop_attr accumulation (la_f per lane), computes
// the self-loop LAST via readlane broadcasts, stores la for layers 1-2.
// LAYER0=0: self-loop FIRST, byte-identical structure to round 7.

template <int LAYER0>
__global__ __launch_bounds__(256) void gat_aggregate(
    const __half2* __restrict__ xl, const __half2* __restrict__ xr,
    const int* __restrict__ rowptr, const int2* __restrict__ csr,
    const float* __restrict__ ea, float* __restrict__ la,
    const float* __restrict__ We, const float* __restrict__ att,
    const float* __restrict__ bias, float* __restrict__ hout, int relu) {
  int wid = threadIdx.x >> 6, lane = threadIdx.x & 63;
  int v = __builtin_amdgcn_readfirstlane(blockIdx.x * 4 + wid);
  if (v >= NN) return;
  int c = 2 * lane;
  v2f wec[16];
#pragma unroll
  for (int k = 0; k < 16; k++) wec[k] = *(const v2f*)(We + k * 128 + c);
  const float L2E = 1.44269504088896340736f;
  v2f av = *(const v2f*)(att + c) * L2E;
  v2f xrv = h2f(xr[(size_t)v * 64 + lane]);

  auto score = [&](int u, const float* eaP, v2f& xu) -> float {
    xu = h2f(xl[(size_t)u * 64 + lane]);
    v2f m = xrv + xu;
#pragma unroll
    for (int k = 0; k < 16; k++) {
      float e = eaP[k];  // wave-uniform -> scalar load
      m = __builtin_elementwise_fma((v2f){e, e}, wec[k], m);
    }
    m = __builtin_elementwise_max(m, 0.2f * m);  // LeakyReLU
    v2f qq = av * m;
    return bfly8(qq.x + qq.y);
  };

  int d16 = lane & 15;
  v2f acc = (v2f){0.f, 0.f};
  float den = 0.f;
  float la_f = 0.f;
  if (!LAYER0) {  // self loop first (la already available)
    v2f xu;
    float p = score(v, la + (size_t)v * 16, xu);
    float w = EXP2(p);
    den = w;
    acc = (v2f){w, w} * xu;
  }
  int start = __builtin_amdgcn_readfirstlane(rowptr[v]);
  int end = __builtin_amdgcn_readfirstlane(rowptr[v + 1]);
  int j = start;
  for (; j + 4 <= end; j += 4) {
    int2 e0 = csr[j], e1 = csr[j + 1], e2 = csr[j + 2], e3 = csr[j + 3];
    int u0 = __builtin_amdgcn_readfirstlane(e0.x);
    int u1 = __builtin_amdgcn_readfirstlane(e1.x);
    int u2 = __builtin_amdgcn_readfirstlane(e2.x);
    int u3 = __builtin_amdgcn_readfirstlane(e3.x);
    const float* p0 = ea + (size_t)__builtin_amdgcn_readfirstlane(e0.y) * 16;
    const float* p1 = ea + (size_t)__builtin_amdgcn_readfirstlane(e1.y) * 16;
    const float* p2 = ea + (size_t)__builtin_amdgcn_readfirstlane(e2.y) * 16;
    const float* p3 = ea + (size_t)__builtin_amdgcn_readfirstlane(e3.y) * 16;
    if (LAYER0) la_f += (p0[d16] + p1[d16]) + (p2[d16] + p3[d16]);
    v2f x0, x1, x2, x3;
    float s0 = score(u0, p0, x0);
    float s1 = score(u1, p1, x1);
    float s2 = score(u2, p2, x2);
    float s3 = score(u3, p3, x3);
    float w0 = EXP2(s0), w1 = EXP2(s1), w2 = EXP2(s2), w3 = EXP2(s3);
    den += (w0 + w1) + (w2 + w3);
    acc = __builtin_elementwise_fma((v2f){w0, w0}, x0,
          __builtin_elementwise_fma((v2f){w1, w1}, x1,
          __builtin_elementwise_fma((v2f){w2, w2}, x2,
          __builtin_elementwise_fma((v2f){w3, w3}, x3, acc))));
  }
  for (; j < end; ++j) {
    int2 e0 = csr[j];
    int u = __builtin_amdgcn_readfirstlane(e0.x);
    const float* p0 = ea + (size_t)__builtin_amdgcn_readfirstlane(e0.y) * 16;
    if (LAYER0) la_f += p0[d16];
    v2f xu;
    float p = score(u, p0, xu);
    float w = EXP2(p);
    den += w;
    acc = __builtin_elementwise_fma((v2f){w, w}, xu, acc);
  }
  if (LAYER0) {  // self loop last, with freshly computed loop_attr
    int deg = end - start;
    float invdeg = (deg > 0) ? 1.f / (float)deg : 0.f;
    la_f *= invdeg;
    if (lane < 16) la[(size_t)v * 16 + d16] = la_f;
    v2f xu = h2f(xl[(size_t)v * 64 + lane]);
    v2f m = xrv + xu;
#pragma unroll
    for (int k = 0; k < 16; k++) {
      float e = __int_as_float(__builtin_amdgcn_readlane(__float_as_int(la_f), k));
      m = __builtin_elementwise_fma((v2f){e, e}, wec[k], m);
    }
    m = __builtin_elementwise_max(m, 0.2f * m);
    v2f qq = av * m;
    float p = bfly8(qq.x + qq.y);
    float w = EXP2(p);
    den += w;
    acc = __builtin_elementwise_fma((v2f){w, w}, xu, acc);
  }
  float invd = 1.f / den;
  v2f bv = *(const v2f*)(bias + c);
  v2f o = __builtin_elementwise_fma(acc, (v2f){invd, invd}, bv);
  if (relu) o = __builtin_elementwise_max(o, (v2f){0.f, 0.f});
  *(v2f*)(hout + (size_t)v * 128 + c) = o;
}

// ---------------- pooling + MLP ----------------

__global__ void gptr_kernel(const int* __restrict__ batch, int* __restrict__ gptr) {
  int g = blockIdx.x * 256 + threadIdx.x;
  if (g > GG) return;
  int lo = 0, hi = NN;
  while (lo < hi) {
    int mid = (lo + hi) >> 1;
    if (batch[mid] < g) lo = mid + 1; else hi = mid;
  }
  gptr[g] = lo;
}

__global__ void pool_kernel(const float* __restrict__ h, const int* __restrict__ gptr,
                            float* __restrict__ gp) {
  int gi = blockIdx.x;
  int c = threadIdx.x;  // 128
  int s = gptr[gi], e = gptr[gi + 1];
  float acc = 0.f;
  for (int v = s; v < e; v++) acc += h[(size_t)v * 128 + c];
  gp[gi * 128 + c] = acc;
}

__global__ __launch_bounds__(256) void mlp1_kernel(const float* __restrict__ gp,
                                                   const float* __restrict__ mW1,
                                                   const float* __restrict__ mb1,
                                                   const float* __restrict__ lng,
                                                   const float* __restrict__ lnb,
                                                   float* __restrict__ z) {
  int row = blockIdx.x;
  int t = threadIdx.x;
  __shared__ float gs[128];
  if (t < 128) gs[t] = gp[row * 128 + t];
  __syncthreads();
  int c0 = t, c1 = t + 256;
  float z0 = 0.f, z1 = 0.f;
  for (int k = 0; k < 128; k++) {
    float gk = gs[k];
    z0 = fmaf(gk, mW1[k * 512 + c0], z0);
    z1 = fmaf(gk, mW1[k * 512 + c1], z1);
  }
  z0 += mb1[c0]; z1 += mb1[c1];
  z0 = fmaxf(z0, 0.f); z1 = fmaxf(z1, 0.f);
  float s = z0 + z1, q = z0 * z0 + z1 * z1;
#pragma unroll
  for (int off = 32; off > 0; off >>= 1) {
    s += __shfl_xor(s, off);
    q += __shfl_xor(q, off);
  }
  __shared__ float red[8];
  int lane = t & 63, w = t >> 6;
  if (lane == 0) { red[w] = s; red[4 + w] = q; }
  __syncthreads();
  float S = red[0] + red[1] + red[2] + red[3];
  float Q = red[4] + red[5] + red[6] + red[7];
  float mu = S / 512.f;
  float var = Q / 512.f - mu * mu;
  float inv = 1.f / sqrtf(var + 1e-5f);
  z[row * 512 + c0] = (z0 - mu) * inv * lng[c0] + lnb[c0];
  z[row * 512 + c1] = (z1 - mu) * inv * lng[c1] + lnb[c1];
}

__global__ __launch_bounds__(256) void mlp2_kernel(const float* __restrict__ z,
                                                   const float* __restrict__ mW2,
                                                   const float* __restrict__ mb2,
                                                   float* __restrict__ out) {
  int row = blockIdx.x;
  int t = threadIdx.x;
  __shared__ float zs[512];
  for (int i = t; i < 512; i += 256) zs[i] = z[row * 512 + i];
  __syncthreads();
  int c0 = t, c1 = t + 256;
  float o0 = 0.f, o1 = 0.f;
  for (int k = 0; k < 512; k++) {
    float zk = zs[k];
    o0 = fmaf(zk, mW2[k * 512 + c0], o0);
    o1 = fmaf(zk, mW2[k * 512 + c1], o1);
  }
  out[row * 512 + c0] = o0 + mb2[c0];
  out[row * 512 + c1] = o1 + mb2[c1];
}

// ---------------- launcher ----------------

extern "C" void kernel_launch(void* const* d_in, const int* in_sizes, int n_in,
                              void* d_out, int out_size, void* d_ws, size_t ws_size,
                              hipStream_t stream) {
  const float* x = (const float*)d_in[0];
  const int* ei = (const int*)d_in[1];
  const int* srcE = ei;
  const int* dstE = ei + EE;
  const float* ea = (const float*)d_in[2];
  const int* batch = (const int*)d_in[3];
  const float* Wl[3] = {(const float*)d_in[4], (const float*)d_in[11], (const float*)d_in[18]};
  const float* bl[3] = {(const float*)d_in[5], (const float*)d_in[12], (const float*)d_in[19]};
  const float* Wr[3] = {(const float*)d_in[6], (const float*)d_in[13], (const float*)d_in[20]};
  const float* br[3] = {(const float*)d_in[7], (const float*)d_in[14], (const float*)d_in[21]};
  const float* Wek[3] = {(const float*)d_in[8], (const float*)d_in[15], (const float*)d_in[22]};
  const float* attk[3] = {(const float*)d_in[9], (const float*)d_in[16], (const float*)d_in[23]};
  const float* bk[3] = {(const float*)d_in[10], (const float*)d_in[17], (const float*)d_in[24]};
  const float* mW1 = (const float*)d_in[25];
  const float* mb1 = (const float*)d_in[26];
  const float* lng = (const float*)d_in[27];
  const float* lnb = (const float*)d_in[28];
  const float* mW2 = (const float*)d_in[29];
  const float* mb2 = (const float*)d_in[30];
  float* outp = (float*)d_out;

  char* W = (char*)d_ws;
  size_t off = 0;
  auto take = [&](size_t b) -> void* {
    void* p = W + off;
    off += (b + 255) & ~(size_t)255;
    return p;
  };
  int* cnt = (int*)take(NN * 4);
  int* rowptr = (int*)take((NN + 1) * 4);
  int* bsums = (int*)take(64 * 4);
  int* bscan = (int*)take(64 * 4);
  int* dummy = (int*)take(64 * 4);
  int2* csr = (int2*)take((size_t)EE * 8);
  float* la = (float*)take((size_t)NN * 16 * 4);
  __half2* xl = (__half2*)take((size_t)NN * 64 * 4);
  __half2* xr = (__half2*)take((size_t)NN * 64 * 4);
  float* hbuf = (float*)take((size_t)NN * HID_ * 4);
  int* gptr = (int*)take((GG + 1) * 4);
  float* gpool = (float*)take((size_t)GG * HID_ * 4);
  float* z = (float*)take((size_t)GG * MH_ * 4);
  (void)ws_size; (void)n_in; (void)in_sizes; (void)out_size;

  // CSR build
  hipMemsetAsync(cnt, 0, NN * 4, stream);
  hist_kernel<<<(EE / 4 + 255) / 256, 256, 0, stream>>>((const int4*)dstE, cnt);
  scan1_kernel<<<49, 256, 0, stream>>>(cnt, NN, rowptr + 1, bsums);
  scan1_kernel<<<1, 256, 0, stream>>>(bsums, 49, bscan, dummy);
  scan_add_kernel<<<(NN + 255) / 256, 256, 0, stream>>>(rowptr, bscan, NN);
  hipMemsetAsync(cnt, 0, NN * 4, stream);
  scatter_kernel<<<(EE / 4 + 255) / 256, 256, 0, stream>>>((const int4*)srcE, (const int4*)dstE,
                                                           rowptr, cnt, csr);

  // 3 GATv2 layers (layer 0 fuses loop_attr computation; no separate loopattr pass)
  for (int l = 0; l < 3; l++) {
    if (l == 0)
      node_transform<FIN><<<(NN + 31) / 32, 256, 0, stream>>>(x, Wl[0], bl[0], Wr[0], br[0],
                                                              xl, xr, NN);
    else
      node_transform<HID_><<<(NN + 31) / 32, 256, 0, stream>>>(hbuf, Wl[l], bl[l], Wr[l], br[l],
                                                               xl, xr, NN);
    if (l == 0)
      gat_aggregate<1><<<(NN + 3) / 4, 256, 0, stream>>>(xl, xr, rowptr, csr, ea, la,
                                                         Wek[0], attk[0], bk[0], hbuf, 1);
    else
      gat_aggregate<0><<<(NN + 3) / 4, 256, 0, stream>>>(xl, xr, rowptr, csr, ea, la,
                                                         Wek[l], attk[l], bk[l], hbuf,
                                                         (l < 2) ? 1 : 0);
  }

  // pooling + MLP head
  gptr_kernel<<<3, 256, 0, stream>>>(batch, gptr);
  pool_kernel<<<GG, 128, 0, stream>>>(hbuf, gptr, gpool);
  mlp1_kernel<<<GG, 256, 0, stream>>>(gpool, mW1, mb1, lng, lnb, z);
  mlp2_kernel<<<GG, 256, 0, stream>>>(z, mW2, mb2, outp);
}